// Round 3
// baseline (91.710 us; speedup 1.0000x reference)
//
#include <hip/hip_runtime.h>

#define THREADS 512
#define NB      8
#define NBLK    (16384 / NB)   // 2048 blocks

typedef float    v4f    __attribute__((ext_vector_type(4)));
typedef short    bf16x8 __attribute__((ext_vector_type(8)));
typedef unsigned u32x4  __attribute__((ext_vector_type(4)));

// packed (i<<3)|j for the 28 upper-triangle pairs of G=8
__constant__ unsigned char c_pair[28] = {
  1,2,3,4,5,6,7, 10,11,12,13,14,15, 19,20,21,22,23, 28,29,30,31, 37,38,39, 46,47, 55
};

// LDS layout (bytes); K-major bf16 rows of 256B, XOR-swizzled:
//   byte = row*256 + ((k*2) ^ ((row&7)<<4))
#define OFF_A    0        // 16KB node [64][128]     ; later sGp[8][128] (2KB used)
#define OFF_GL   16384    // 4KB  glob [16][128] (rows 8..15 zero)
#define OFF_SB   20480    // 32KB W^T staging rounds ; later Pa rows 0..63, Pb rows 64..127
#define OFF_W2   53248    // 16KB W2^T [64][128]
#define OFF_B1V  69632    // 512  b1 f32[128]
#define OFF_B2V  70144    // 256  b2 f32[64]
#define OFF_W3V  70400    // 256  W3 f32[64]
#define SMEM_BYTES 70656  // 2 blocks/CU (2*70656 <= 163840)

static __device__ __forceinline__ unsigned asu(float f){ union{float f;unsigned u;}v; v.f=f; return v.u; }
static __device__ __forceinline__ float lo2f(unsigned d){ union{unsigned u;float f;}v; v.u = d<<16; return v.f; }
static __device__ __forceinline__ float hi2f(unsigned d){ union{unsigned u;float f;}v; v.u = d & 0xffff0000u; return v.f; }
// pack two f32 -> bf16x2 (truncation); 1 v_perm_b32
static __device__ __forceinline__ unsigned pkt(float lo, float hi){
  return __builtin_amdgcn_perm(asu(hi), asu(lo), 0x07060302u);
}

__global__ __launch_bounds__(THREADS, 4)
void docking_fused(const float* __restrict__ node, const float* __restrict__ glob,
                   const int* __restrict__ dmask,
                   const float* __restrict__ W1, const float* __restrict__ b1,
                   const float* __restrict__ W2, const float* __restrict__ b2,
                   const float* __restrict__ W3, const float* __restrict__ b3,
                   float* __restrict__ outp)
{
  __shared__ __align__(16) char smem[SMEM_BYTES];
  const int tid = threadIdx.x;
  const int bb0 = blockIdx.x * NB;
  const size_t nrow0 = (size_t)bb0 * 8;
  const float bias3 = *b3;

  // ---------------- stage 0 ----------------
  if (tid < 128)      ((float*)(smem + OFF_B1V))[tid]       = b1[tid];
  else if (tid < 192) ((float*)(smem + OFF_B2V))[tid - 128] = b2[tid - 128];
  else if (tid < 256) ((float*)(smem + OFF_W3V))[tid - 192] = W3[tid - 192];

  // node rows -> sA (64 rows)
  for (int idx = tid; idx < 64 * 32; idx += THREADS) {      // 4 iters
    const int r = idx >> 5, q = idx & 31;
    const float4 f = *(const float4*)(node + (nrow0 + (size_t)r) * 128 + q * 4);
    int2 w; w.x = (int)pkt(f.x, f.y); w.y = (int)pkt(f.z, f.w);
    *(int2*)(smem + OFF_A + r * 256 + ((q * 8) ^ ((r & 7) << 4))) = w;
  }
  // glob rows -> sGl (16 rows, 8..15 zeroed)
  for (int idx = tid; idx < 16 * 32; idx += THREADS) {      // 1 iter
    const int r = idx >> 5, q = idx & 31;
    float4 f = make_float4(0.f, 0.f, 0.f, 0.f);
    if (r < NB) f = *(const float4*)(glob + (size_t)(bb0 + r) * 128 + q * 4);
    int2 w; w.x = (int)pkt(f.x, f.y); w.y = (int)pkt(f.z, f.w);
    *(int2*)(smem + OFF_GL + r * 256 + ((q * 8) ^ ((r & 7) << 4))) = w;
  }
  // W2 -> sW2t[c][k]  (lane-remap: 8 cols x 8 kp per wave -> 2-way banks)
  for (int idx = tid; idx < 4096; idx += THREADS) {         // 8 iters
    const int cl = idx & 7, kl = (idx >> 3) & 7, ch = (idx >> 6) & 7, kh = idx >> 9;
    const int c = cl | (ch << 3), kp = kl | (kh << 3);
    const float a  = W2[(size_t)(2 * kp) * 64 + c];
    const float b_ = W2[(size_t)(2 * kp + 1) * 64 + c];
    *(unsigned*)(smem + OFF_W2 + c * 256 + ((kp * 4) ^ ((c & 7) << 4))) = pkt(a, b_);
  }
  // W1 part -> sB (32KB round): rowOff in {0,128,256}
  auto stageB = [&](int rowOff) {
    for (int idx = tid; idx < 8192; idx += THREADS) {       // 16 iters
      const int cl = idx & 7, kl = (idx >> 3) & 7, ch = (idx >> 6) & 15, kh = idx >> 10;
      const int c = cl | (ch << 3), kp = kl | (kh << 3);
      const float a  = W1[(size_t)(rowOff + 2 * kp) * 128 + c];
      const float b_ = W1[(size_t)(rowOff + 2 * kp + 1) * 128 + c];
      *(unsigned*)(smem + OFF_SB + c * 256 + ((kp * 4) ^ ((c & 7) << 4))) = pkt(a, b_);
    }
  };
  stageB(0);          // Ba^T
  __syncthreads();

  // ---------------- phase 1: three proj GEMM rounds ----------------
  const int wave = tid >> 6, lane = tid & 63;
  const int lrow = lane & 15;
  const int lko  = (lane >> 4) * 8;
  const int wmt = wave >> 1, wnh = wave & 1;   // wave: 1 m-tile x 4 n-tiles (half of N=128)
  const v4f vzero = {0.f, 0.f, 0.f, 0.f};

  bf16x8 af[4];
#pragma unroll
  for (int ks = 0; ks < 4; ++ks) {
    const int r = wmt * 16 + lrow;
    af[ks] = *(const bf16x8*)(smem + OFF_A + r * 256 + (((ks * 32 + lko) * 2) ^ ((r & 7) << 4)));
  }

  v4f acc_a[4] = {vzero, vzero, vzero, vzero};
#pragma unroll
  for (int ks = 0; ks < 4; ++ks) {
    const int kb = (ks * 32 + lko) * 2;
#pragma unroll
    for (int nt = 0; nt < 4; ++nt) {
      const int c = wnh * 64 + nt * 16 + lrow;
      const bf16x8 bfr = *(const bf16x8*)(smem + OFF_SB + c * 256 + (kb ^ ((c & 7) << 4)));
      acc_a[nt] = __builtin_amdgcn_mfma_f32_16x16x32_bf16(af[ks], bfr, acc_a[nt], 0, 0, 0);
    }
  }
  __syncthreads();
  stageB(128);        // Bb^T
  __syncthreads();
  v4f acc_b[4] = {vzero, vzero, vzero, vzero};
#pragma unroll
  for (int ks = 0; ks < 4; ++ks) {
    const int kb = (ks * 32 + lko) * 2;
#pragma unroll
    for (int nt = 0; nt < 4; ++nt) {
      const int c = wnh * 64 + nt * 16 + lrow;
      const bf16x8 bfr = *(const bf16x8*)(smem + OFF_SB + c * 256 + (kb ^ ((c & 7) << 4)));
      acc_b[nt] = __builtin_amdgcn_mfma_f32_16x16x32_bf16(af[ks], bfr, acc_b[nt], 0, 0, 0);
    }
  }
  __syncthreads();
  stageB(256);        // Bg^T
  __syncthreads();
  v4f accg = vzero;
#pragma unroll
  for (int ks = 0; ks < 4; ++ks) {
    const int kb = (ks * 32 + lko) * 2;
    const bf16x8 ag = *(const bf16x8*)(smem + OFF_GL + lrow * 256 + (kb ^ ((lrow & 7) << 4)));
    const int cg = wave * 16 + lrow;
    const bf16x8 bg = *(const bf16x8*)(smem + OFF_SB + cg * 256 + (kb ^ ((cg & 7) << 4)));
    accg = __builtin_amdgcn_mfma_f32_16x16x32_bf16(ag, bg, accg, 0, 0, 0);
  }
  __syncthreads();    // all sB reads done

  // write Pa (rows 0..63) / Pb (rows 64..127) over sB; gp+b1 over sA
  {
    const int rgb = (lane >> 4) * 4;
#pragma unroll
    for (int nt = 0; nt < 4; ++nt) {
      const int c = wnh * 64 + nt * 16 + lrow;
#pragma unroll
      for (int rg = 0; rg < 4; ++rg) {
        const int m = wmt * 16 + rgb + rg;
        const int sw = (c * 2) ^ ((m & 7) << 4);
        *(unsigned short*)(smem + OFF_SB + m * 256 + sw)        = (unsigned short)(asu(acc_a[nt][rg]) >> 16);
        *(unsigned short*)(smem + OFF_SB + (64 + m) * 256 + sw) = (unsigned short)(asu(acc_b[nt][rg]) >> 16);
      }
    }
    const int cg = wave * 16 + lrow;
    const float b1c = ((const float*)(smem + OFF_B1V))[cg];
#pragma unroll
    for (int rg = 0; rg < 4; ++rg) {
      const int bbr = rgb + rg;
      if (bbr < NB)
        *(unsigned short*)(smem + OFF_A + bbr * 256 + ((cg * 2) ^ ((bbr & 7) << 4))) =
            (unsigned short)(asu(accg[rg] + b1c) >> 16);
    }
  }
  __syncthreads();

  // ---------------- phase 2: pair MLP, barrier-free ----------------
  float b2n[4], w3n[4];
#pragma unroll
  for (int nt = 0; nt < 4; ++nt) {
    const int n = nt * 16 + lrow;
    b2n[nt] = ((const float*)(smem + OFF_B2V))[n];
    w3n[nt] = ((const float*)(smem + OFF_W3V))[n];
  }

  for (int t = wave; t < 14; t += 8) {          // 14 tiles x 16 pair-rows = 224
    const int r  = t * 16 + lrow;
    const int bb = (r * 9363) >> 18;            // r/28 for r<2340
    const int p  = r - bb * 28;
    const unsigned pr8 = c_pair[p];
    const int mi = bb * 8 + (int)(pr8 >> 3);
    const int mj = 64 + bb * 8 + (int)(pr8 & 7);

    v4f acc2[4] = {vzero, vzero, vzero, vzero};
#pragma unroll
    for (int ks = 0; ks < 4; ++ks) {
      const int kb = (ks * 32 + lko) * 2;
      const u32x4 va = *(const u32x4*)(smem + OFF_SB + mi * 256 + (kb ^ ((mi & 7) << 4)));
      const u32x4 vb = *(const u32x4*)(smem + OFF_SB + mj * 256 + (kb ^ ((mj & 7) << 4)));
      const u32x4 vg = *(const u32x4*)(smem + OFF_A  + bb * 256 + (kb ^ ((bb & 7) << 4)));
      u32x4 a2;
#pragma unroll
      for (int w = 0; w < 4; ++w) {
        const float lo = fmaxf(lo2f(va[w]) + lo2f(vb[w]) + lo2f(vg[w]), 0.0f);
        const float hi = fmaxf(hi2f(va[w]) + hi2f(vb[w]) + hi2f(vg[w]), 0.0f);
        a2[w] = pkt(lo, hi);
      }
      union { u32x4 u; bf16x8 h; } cv; cv.u = a2;
#pragma unroll
      for (int nt = 0; nt < 4; ++nt) {
        const int c = nt * 16 + lrow;
        const bf16x8 w2fr = *(const bf16x8*)(smem + OFF_W2 + c * 256 + (kb ^ ((c & 7) << 4)));
        acc2[nt] = __builtin_amdgcn_mfma_f32_16x16x32_bf16(cv.h, w2fr, acc2[nt], 0, 0, 0);
      }
    }
    // epilogue: score = b3 + sum_n relu(h2 + b2) * W3
    float part[4] = {0.f, 0.f, 0.f, 0.f};
#pragma unroll
    for (int nt = 0; nt < 4; ++nt)
#pragma unroll
      for (int rg = 0; rg < 4; ++rg)
        part[rg] += fmaxf(acc2[nt][rg] + b2n[nt], 0.0f) * w3n[nt];
#pragma unroll
    for (int mk = 1; mk < 16; mk <<= 1)
#pragma unroll
      for (int rg = 0; rg < 4; ++rg) part[rg] += __shfl_xor(part[rg], mk, 16);

    if ((lane & 15) == 0) {
      const int rb = t * 16 + (lane >> 4) * 4;
#pragma unroll
      for (int rg = 0; rg < 4; ++rg) {
        const int rr = rb + rg;
        const int b2_ = (rr * 9363) >> 18;
        const int p2  = rr - b2_ * 28;
        const size_t o = (size_t)(bb0 + b2_) * 28 + p2;
        const float sc = part[rg] + bias3;
        outp[o] = dmask[o] ? sc : -1.0e9f;
      }
    }
  }
}

extern "C" void kernel_launch(void* const* d_in, const int* in_sizes, int n_in,
                              void* d_out, int out_size, void* d_ws, size_t ws_size,
                              hipStream_t stream) {
  (void)in_sizes; (void)n_in; (void)out_size; (void)d_ws; (void)ws_size;
  const float* node = (const float*)d_in[0];
  const float* glob = (const float*)d_in[1];
  // d_in[2] = group_mask (unused by reference)
  const int* dmsk   = (const int*)d_in[3];   // bool -> int32 on upload
  // d_in[4] = batch (unused by reference)
  const float* W1 = (const float*)d_in[5];
  const float* b1 = (const float*)d_in[6];
  const float* W2 = (const float*)d_in[7];
  const float* b2 = (const float*)d_in[8];
  const float* W3 = (const float*)d_in[9];
  const float* b3 = (const float*)d_in[10];
  float* outp = (float*)d_out;
  docking_fused<<<NBLK, THREADS, 0, stream>>>(node, glob, dmsk, W1, b1, W2, b2, W3, b3, outp);
}